// Round 13
// baseline (245.771 us; speedup 1.0000x reference)
//
#include <hip/hip_runtime.h>
#include <hip/hip_fp16.h>
#include <math.h>

#define N_NODES 50000
#define N_EDGES 1600000
#define DIM     128
#define N_GRAPHS 64

typedef unsigned int uint32;
typedef __attribute__((ext_vector_type(8))) short bf16x8;
typedef __attribute__((ext_vector_type(4))) float f32x4;

static __device__ __forceinline__ ushort f2b(float f) {
    uint32 u = __float_as_uint(f);
    uint32 r = (u + 0x7fffu + ((u >> 16) & 1u)) >> 16;   // RNE
    return (ushort)r;
}
static __device__ __forceinline__ float b2f(ushort h) {
    return __uint_as_float(((uint32)h) << 16);
}
// fp8 e5m2 = top byte of fp16. Encode f32 -> f16 (RNE) -> RNE to top byte.
static __device__ __forceinline__ unsigned char f2e5(float f) {
    ushort hb = __half_as_ushort(__float2half(f));
    return (unsigned char)(((uint32)hb + 0x7fu + ((hb >> 8) & 1u)) >> 8);
}
union h2u_t { uint32 u; __half2 h; };
static __device__ __forceinline__ __half2 u2h2(uint32 u) { h2u_t t; t.u = u; return t.h; }
static __device__ __forceinline__ uint32 h2u(__half2 h)  { h2u_t t; t.h = h; return t.u; }
// bytes {0,1} / {2,3} of v -> fp16 pair (each byte into high byte of an fp16)
static __device__ __forceinline__ __half2 dec01(uint32 v) {
    return u2h2(__builtin_amdgcn_perm(v, 0u, 0x05000400u));
}
static __device__ __forceinline__ __half2 dec23(uint32 v) {
    return u2h2(__builtin_amdgcn_perm(v, 0u, 0x07000600u));
}
// stored position p -> true feature index (p = m*8 + nt, f = nt*16 + m)
static __device__ __forceinline__ int permf(int p) { return ((p & 7) << 4) + (p >> 3); }

// ---- bucketed CSR build (no node-level global atomics anywhere) ----
#define NBUK 196             // ceil(50000/256), bucket = node >> 8
#define CAP  16384           // slack per bucket (mean 8192, sd ~90)
#define PB1  512
#define CHUNK1 (N_EDGES / PB1)   // 3125 exact

// W transposes (3x, k-permuted for layers 2&3) + gfill init, one launch.
__global__ __launch_bounds__(256) void prep_k(const float* __restrict__ W1,
                                              const float* __restrict__ W2,
                                              const float* __restrict__ W3,
                                              ushort* __restrict__ wt,
                                              int* __restrict__ gfill) {
    int blk = blockIdx.x;
    if (blk < 192) {
        int w = blk >> 6;
        const float* W = (w == 0) ? W1 : (w == 1) ? W2 : W3;
        ushort* o = wt + w * (DIM * DIM);
        int t = (blk & 63) * 256 + threadIdx.x;   // 0..16383
        int n = t >> 7, kp = t & 127;
        int f = (w == 0) ? kp : permf(kp);   // layer 1 A is true-order; 2,3 p-order
        o[n * 128 + kp] = f2b(W[f * 128 + n]);
    } else {
        int t = threadIdx.x;
        if (t < NBUK) gfill[t] = t * CAP;
    }
}

__global__ __launch_bounds__(256) void bin_k(const int* __restrict__ col,
                                             const int* __restrict__ row,
                                             int* __restrict__ gfill,
                                             uint32* __restrict__ packed) {
    __shared__ int hist[NBUK];
    __shared__ int cur[NBUK];
    int tid = threadIdx.x;
    for (int t = tid; t < NBUK; t += 256) hist[t] = 0;
    __syncthreads();
    int start = blockIdx.x * CHUNK1, end = start + CHUNK1;
    for (int e = start + tid; e < end; e += 256)
        atomicAdd(&hist[col[e] >> 8], 1);
    __syncthreads();
    for (int t = tid; t < NBUK; t += 256) {
        int h = hist[t];
        cur[t] = h ? atomicAdd(&gfill[t], h) : 0;
    }
    __syncthreads();
    for (int e = start + tid; e < end; e += 256) {
        int c = col[e];
        int r = row[e];
        int pos = atomicAdd(&cur[c >> 8], 1);
        packed[pos] = ((uint32)(c & 255) << 16) | (uint32)r;
    }
}

// per bucket: inline bucket-base scan, histogram -> cnt/offs/dis, rank-scatter csr (ushort).
__global__ __launch_bounds__(256) void bucket_k(const uint32* __restrict__ packed,
                                                const int* __restrict__ gfill,
                                                int* __restrict__ cnt,
                                                int* __restrict__ offs,
                                                float* __restrict__ dis,
                                                ushort* __restrict__ csr) {
    __shared__ int bsm[256];
    __shared__ int hist[256];
    __shared__ int sm[256];
    __shared__ int lo[256];
    __shared__ int rank[256];
    int b = blockIdx.x, tid = threadIdx.x;

    int bsz = (tid < NBUK) ? (gfill[tid] - tid * CAP) : 0;
    bsm[tid] = bsz;
    __syncthreads();
    for (int off = 1; off < 256; off <<= 1) {
        int u = 0;
        if (tid >= off) u = bsm[tid - off];
        __syncthreads();
        if (tid >= off) bsm[tid] += u;
        __syncthreads();
    }
    int size = gfill[b] - b * CAP;
    int gb = bsm[b] - size;   // exclusive base of this bucket

    const uint32* pk = packed + (size_t)b * CAP;
    hist[tid] = 0; rank[tid] = 0;
    __syncthreads();
    for (int e = tid; e < size; e += 256) atomicAdd(&hist[pk[e] >> 16], 1);
    __syncthreads();
    int h = hist[tid];
    sm[tid] = h;
    __syncthreads();
    for (int off = 1; off < 256; off <<= 1) {
        int u = 0;
        if (tid >= off) u = sm[tid - off];
        __syncthreads();
        if (tid >= off) sm[tid] += u;
        __syncthreads();
    }
    lo[tid] = sm[tid] - h;
    int node = (b << 8) + tid;
    if (node < N_NODES) {
        cnt[node]  = h;
        offs[node] = gb + lo[tid];
        dis[node]  = rsqrtf((float)h + 1.0f);
    }
    __syncthreads();
    for (int e = tid; e < size; e += 256) {
        uint32 p = pk[e];
        int cl = p >> 16;
        int r = atomicAdd(&rank[cl], 1);
        csr[gb + lo[cl] + r] = (ushort)(p & 0xffffu);
    }
}

// ---------------- fp32 -> bf16 convert ----------------
__global__ __launch_bounds__(256) void conv_k(const float* __restrict__ x, ushort* __restrict__ xb) {
    int i = blockIdx.x * blockDim.x + threadIdx.x;
    const int n4 = N_NODES * DIM / 4;
    if (i >= n4) return;
    float4 v = ((const float4*)x)[i];
    ushort4 o;
    o.x = f2b(v.x); o.y = f2b(v.y); o.z = f2b(v.z); o.w = f2b(v.w);
    ((ushort4*)xb)[i] = o;
}

// ---------------- g = fp8e5m2( (h @ W) * dis )  via MFMA ----------------
// 4 waves/block; wave = 32 rows x 128 cols. Output stored in p-order:
// feature f=nt*16+m goes to byte p=m*8+nt -> lane's 8 bytes contiguous -> uint2 store.
__global__ __launch_bounds__(256) void gemm_mfma_k(const ushort* __restrict__ xb,
                                                   const ushort* __restrict__ wt,
                                                   const float* __restrict__ dis,
                                                   unsigned char* __restrict__ gb) {
    int wid  = threadIdx.x >> 6;
    int lane = threadIdx.x & 63;
    int r0 = blockIdx.x * 128 + wid * 32;
    int m  = lane & 15;
    int kg = lane >> 4;

    int arow0 = r0 + m;
    int arow1 = r0 + 16 + m;
    if (arow0 >= N_NODES) arow0 = N_NODES - 1;   // clamp; stores guarded
    if (arow1 >= N_NODES) arow1 = N_NODES - 1;
    const ushort* abase0 = xb + (size_t)arow0 * DIM + kg * 8;
    const ushort* abase1 = xb + (size_t)arow1 * DIM + kg * 8;
    const ushort* wbase  = wt + (size_t)m * DIM + kg * 8;

    f32x4 acc[2][8];
    #pragma unroll
    for (int hh = 0; hh < 2; ++hh)
        #pragma unroll
        for (int nt = 0; nt < 8; ++nt) acc[hh][nt] = (f32x4){0.f, 0.f, 0.f, 0.f};

    #pragma unroll
    for (int kb = 0; kb < 4; ++kb) {
        bf16x8 a0 = *(const bf16x8*)(abase0 + kb * 32);
        bf16x8 a1 = *(const bf16x8*)(abase1 + kb * 32);
        #pragma unroll
        for (int nt = 0; nt < 8; ++nt) {
            bf16x8 b = *(const bf16x8*)(wbase + (size_t)nt * 16 * DIM + kb * 32);
            acc[0][nt] = __builtin_amdgcn_mfma_f32_16x16x32_bf16(a0, b, acc[0][nt], 0, 0, 0);
            acc[1][nt] = __builtin_amdgcn_mfma_f32_16x16x32_bf16(a1, b, acc[1][nt], 0, 0, 0);
        }
    }

    #pragma unroll
    for (int hh = 0; hh < 2; ++hh) {
        int orow0 = r0 + hh * 16 + kg * 4;
        #pragma unroll
        for (int i = 0; i < 4; ++i) {
            int rr = orow0 + i;
            if (rr >= N_NODES) continue;
            float dsc = dis[rr];
            uint32 u0 = (uint32)f2e5(acc[hh][0][i] * dsc)
                      | ((uint32)f2e5(acc[hh][1][i] * dsc) << 8)
                      | ((uint32)f2e5(acc[hh][2][i] * dsc) << 16)
                      | ((uint32)f2e5(acc[hh][3][i] * dsc) << 24);
            uint32 u1 = (uint32)f2e5(acc[hh][4][i] * dsc)
                      | ((uint32)f2e5(acc[hh][5][i] * dsc) << 8)
                      | ((uint32)f2e5(acc[hh][6][i] * dsc) << 16)
                      | ((uint32)f2e5(acc[hh][7][i] * dsc) << 24);
            uint2 u = make_uint2(u0, u1);
            *(uint2*)(gb + (size_t)rr * DIM + m * 8) = u;
        }
    }
}

// ---------------- out = bf16( relu(dis_i * (g_i + sum_j g_j) + b) ) ----------------
// 16-lane row segments: 4 edges per gather instruction (4 lane-groups),
// 8 uint2 loads in flight = 32 rows outstanding. Uniform shfl broadcasts + cndmask.
__global__ __launch_bounds__(256) void agg_k(const unsigned char* __restrict__ gb,
                                             const float* __restrict__ dis,
                                             const ushort* __restrict__ csr,
                                             const int* __restrict__ offs,
                                             const int* __restrict__ cnt,
                                             const float* __restrict__ bias,
                                             ushort* __restrict__ outb) {
    int lane = threadIdx.x & 63;
    int node = blockIdx.x * 4 + (threadIdx.x >> 6);
    if (node >= N_NODES) return;
    int eg = lane >> 4;                 // edge-group 0..3
    uint32 c8 = (uint32)(lane & 15) << 3;   // byte offset of this lane's 8-feature segment
    const unsigned char* gq = gb + c8;

    // self term: only eg==0 lanes add it
    uint2 sv = *(const uint2*)(gq + ((uint32)node << 7));
    if (eg) { sv.x = 0; sv.y = 0; }
    __half2 a0 = dec01(sv.x), a1 = dec23(sv.x);
    __half2 a2 = dec01(sv.y), a3 = dec23(sv.y);

    int base = offs[node];
    int c = cnt[node];
    for (int s0 = 0; s0 < c; s0 += 64) {
        int rem = c - s0;
        int m = rem < 64 ? rem : 64;
        int idx = 0;
        if (lane < m) idx = csr[base + s0 + lane];
        int t = 0;
        for (; t + 32 <= m; t += 32) {          // 32 edges (8 quads) in flight
            uint2 v[8];
            #pragma unroll
            for (int p = 0; p < 8; ++p) {
                int tt = t + 4 * p;
                int j0 = __shfl(idx, tt, 64),     j1 = __shfl(idx, tt + 1, 64);
                int j2 = __shfl(idx, tt + 2, 64), j3 = __shfl(idx, tt + 3, 64);
                int jA = (eg & 1) ? j1 : j0;
                int jB = (eg & 1) ? j3 : j2;
                int j  = (eg & 2) ? jB : jA;
                v[p] = *(const uint2*)(gq + ((uint32)j << 7));
            }
            #pragma unroll
            for (int p = 0; p < 8; ++p) {
                a0 = __hadd2(a0, dec01(v[p].x));
                a1 = __hadd2(a1, dec23(v[p].x));
                a2 = __hadd2(a2, dec01(v[p].y));
                a3 = __hadd2(a3, dec23(v[p].y));
            }
        }
        for (; t < m; t += 4) {                 // tail quads, masked
            int j0 = __shfl(idx, t, 64);
            int j1 = __shfl(idx, t + 1 <= 63 ? t + 1 : 63, 64);
            int j2 = __shfl(idx, t + 2 <= 63 ? t + 2 : 63, 64);
            int j3 = __shfl(idx, t + 3 <= 63 ? t + 3 : 63, 64);
            int jA = (eg & 1) ? j1 : j0;
            int jB = (eg & 1) ? j3 : j2;
            int j  = (eg & 2) ? jB : jA;
            uint2 v = *(const uint2*)(gq + ((uint32)j << 7));
            if (t + eg >= m) { v.x = 0; v.y = 0; }
            a0 = __hadd2(a0, dec01(v.x));
            a1 = __hadd2(a1, dec23(v.x));
            a2 = __hadd2(a2, dec01(v.y));
            a3 = __hadd2(a3, dec23(v.y));
        }
    }

    // reduce across the 4 edge-groups (lanes q, q+16, q+32, q+48)
    a0 = __hadd2(a0, u2h2((uint32)__shfl_xor((int)h2u(a0), 16, 64)));
    a1 = __hadd2(a1, u2h2((uint32)__shfl_xor((int)h2u(a1), 16, 64)));
    a2 = __hadd2(a2, u2h2((uint32)__shfl_xor((int)h2u(a2), 16, 64)));
    a3 = __hadd2(a3, u2h2((uint32)__shfl_xor((int)h2u(a3), 16, 64)));
    a0 = __hadd2(a0, u2h2((uint32)__shfl_xor((int)h2u(a0), 32, 64)));
    a1 = __hadd2(a1, u2h2((uint32)__shfl_xor((int)h2u(a1), 32, 64)));
    a2 = __hadd2(a2, u2h2((uint32)__shfl_xor((int)h2u(a2), 32, 64)));
    a3 = __hadd2(a3, u2h2((uint32)__shfl_xor((int)h2u(a3), 32, 64)));

    if (eg == 0) {
        float d = dis[node];
        float f[8];
        f[0] = __low2float(a0); f[1] = __high2float(a0);
        f[2] = __low2float(a1); f[3] = __high2float(a1);
        f[4] = __low2float(a2); f[5] = __high2float(a2);
        f[6] = __low2float(a3); f[7] = __high2float(a3);
        ushort o[8];
        #pragma unroll
        for (int i = 0; i < 8; ++i) {
            float bv = bias[permf(c8 + i)];
            o[i] = f2b(fmaxf(fmaf(f[i], d, bv), 0.f));
        }
        uint4 u;
        u.x = (uint32)o[0] | ((uint32)o[1] << 16);
        u.y = (uint32)o[2] | ((uint32)o[3] << 16);
        u.z = (uint32)o[4] | ((uint32)o[5] << 16);
        u.w = (uint32)o[6] | ((uint32)o[7] << 16);
        *(uint4*)(outb + ((size_t)node << 7) + c8) = u;
    }
}

// ---------------- mean-pool (h in p-order; pooled stays p-order) ----------------
#define POOL_BLOCKS 1024
__global__ __launch_bounds__(128) void pool_k(const ushort* __restrict__ hb,
                                              const int* __restrict__ batch,
                                              float* __restrict__ pooled,
                                              float* __restrict__ counts) {
    const int chunk = (N_NODES + POOL_BLOCKS - 1) / POOL_BLOCKS;  // 49
    int tid = threadIdx.x;
    int start = blockIdx.x * chunk;
    int end = start + chunk; if (end > N_NODES) end = N_NODES;
    if (start >= end) return;

    float acc = 0.f;
    int cur = batch[start];
    int cl = 0;
    for (int n = start; n < end; ++n) {
        int b = batch[n];
        if (b != cur) {
            atomicAdd(&pooled[cur * DIM + tid], acc);
            if (tid == 0) atomicAdd(&counts[cur], (float)cl);
            acc = 0.f; cl = 0; cur = b;
        }
        acc += b2f(hb[((size_t)n << 7) + tid]);
        ++cl;
    }
    atomicAdd(&pooled[cur * DIM + tid], acc);
    if (tid == 0) atomicAdd(&counts[cur], (float)cl);
}

// ---------------- head (pooled in p-order -> permute Wf) ----------------
__global__ void final_k(const float* __restrict__ pooled, const float* __restrict__ counts,
                        const float* __restrict__ Wf, const float* __restrict__ bf,
                        float* __restrict__ out) {
    __shared__ float sred[2];
    int gidx = blockIdx.x;
    int tid = threadIdx.x;   // 128
    float c = fmaxf(counts[gidx], 1.0f);
    float v = pooled[gidx * DIM + tid] / c * Wf[permf(tid)];
    for (int off = 32; off > 0; off >>= 1) v += __shfl_down(v, off, 64);
    if ((tid & 63) == 0) sred[tid >> 6] = v;
    __syncthreads();
    if (tid == 0) {
        float t = sred[0] + sred[1] + bf[0];
        out[gidx] = 1.0f / (1.0f + expf(-t));
    }
}

extern "C" void kernel_launch(void* const* d_in, const int* in_sizes, int n_in,
                              void* d_out, int out_size, void* d_ws, size_t ws_size,
                              hipStream_t stream) {
    const float* x     = (const float*)d_in[0];
    const int*   ei    = (const int*)d_in[1];
    const int*   batch = (const int*)d_in[2];
    const float* W1 = (const float*)d_in[3];  const float* b1 = (const float*)d_in[4];
    const float* W2 = (const float*)d_in[5];  const float* b2 = (const float*)d_in[6];
    const float* W3 = (const float*)d_in[7];  const float* b3 = (const float*)d_in[8];
    const float* Wf = (const float*)d_in[9];  const float* bf = (const float*)d_in[10];
    const int* rowp = ei;              // sources
    const int* colp = ei + N_EDGES;    // targets

    char* ws = (char*)d_ws;
    size_t o = 0;
    auto alloc = [&](size_t bytes) -> void* {
        void* p = ws + o;
        o += (bytes + 255) & ~(size_t)255;
        return p;
    };
    int*    cnt    = (int*)   alloc((size_t)N_NODES * 4);
    int*    offs   = (int*)   alloc((size_t)N_NODES * 4);
    int*    gfill  = (int*)   alloc(256 * 4);
    float*  dis    = (float*) alloc((size_t)N_NODES * 4);
    ushort* csr    = (ushort*)alloc((size_t)N_EDGES * 2);
    uint32* packed = (uint32*)alloc((size_t)NBUK * CAP * 4);
    float*  pooled = (float*) alloc((size_t)(N_GRAPHS * DIM + N_GRAPHS) * 4);
    ushort* wt     = (ushort*)alloc((size_t)3 * DIM * DIM * 2);
    unsigned char* bufA = (unsigned char*)alloc((size_t)N_NODES * DIM);  // g (fp8, p-order)
    ushort* bufB   = (ushort*)alloc((size_t)N_NODES * DIM * 2);          // h (bf16)
    float*  counts = pooled + N_GRAPHS * DIM;

    hipMemsetAsync(pooled, 0, (size_t)(N_GRAPHS * DIM + N_GRAPHS) * 4, stream);

    prep_k<<<193, 256, 0, stream>>>(W1, W2, W3, wt, gfill);
    bin_k<<<PB1, 256, 0, stream>>>(colp, rowp, gfill, packed);
    bucket_k<<<NBUK, 256, 0, stream>>>(packed, gfill, cnt, offs, dis, csr);

    conv_k<<<(N_NODES * DIM / 4 + 255) / 256, 256, 0, stream>>>(x, bufB);

    const int GB = (N_NODES + 127) / 128;   // 391

    // layer 1
    gemm_mfma_k<<<GB, 256, 0, stream>>>(bufB, wt, dis, bufA);
    agg_k<<<(N_NODES + 3) / 4, 256, 0, stream>>>(bufA, dis, csr, offs, cnt, b1, bufB);
    // layer 2
    gemm_mfma_k<<<GB, 256, 0, stream>>>(bufB, wt + DIM * DIM, dis, bufA);
    agg_k<<<(N_NODES + 3) / 4, 256, 0, stream>>>(bufA, dis, csr, offs, cnt, b2, bufB);
    // layer 3
    gemm_mfma_k<<<GB, 256, 0, stream>>>(bufB, wt + 2 * DIM * DIM, dis, bufA);
    agg_k<<<(N_NODES + 3) / 4, 256, 0, stream>>>(bufA, dis, csr, offs, cnt, b3, bufB);

    pool_k<<<POOL_BLOCKS, 128, 0, stream>>>(bufB, batch, pooled, counts);
    final_k<<<N_GRAPHS, 128, 0, stream>>>(pooled, counts, Wf, bf, (float*)d_out);
}

// Round 14
// 239.460 us; speedup vs baseline: 1.0264x; 1.0264x over previous
//
#include <hip/hip_runtime.h>
#include <hip/hip_fp16.h>
#include <math.h>

#define N_NODES 50000
#define N_EDGES 1600000
#define DIM     128
#define N_GRAPHS 64

typedef unsigned int uint32;
typedef __attribute__((ext_vector_type(8))) short bf16x8;
typedef __attribute__((ext_vector_type(4))) float f32x4;

static __device__ __forceinline__ ushort f2b(float f) {
    uint32 u = __float_as_uint(f);
    uint32 r = (u + 0x7fffu + ((u >> 16) & 1u)) >> 16;   // RNE
    return (ushort)r;
}
static __device__ __forceinline__ float b2f(ushort h) {
    return __uint_as_float(((uint32)h) << 16);
}
// fp8 e5m2 = top byte of fp16. Encode f32 -> f16 (RNE) -> RNE to top byte.
static __device__ __forceinline__ unsigned char f2e5(float f) {
    ushort hb = __half_as_ushort(__float2half(f));
    return (unsigned char)(((uint32)hb + 0x7fu + ((hb >> 8) & 1u)) >> 8);
}
union h2u_t { uint32 u; __half2 h; };
static __device__ __forceinline__ __half2 u2h2(uint32 u) { h2u_t t; t.u = u; return t.h; }
static __device__ __forceinline__ uint32 h2u(__half2 h)  { h2u_t t; t.h = h; return t.u; }
// bytes {0,1} / {2,3} of v -> fp16 pair (each byte into high byte of an fp16)
static __device__ __forceinline__ __half2 dec01(uint32 v) {
    return u2h2(__builtin_amdgcn_perm(v, 0u, 0x05000400u));
}
static __device__ __forceinline__ __half2 dec23(uint32 v) {
    return u2h2(__builtin_amdgcn_perm(v, 0u, 0x07000600u));
}
// stored position p -> true feature index (p = m*8 + nt, f = nt*16 + m)
static __device__ __forceinline__ int permf(int p) { return ((p & 7) << 4) + (p >> 3); }

// ---- bucketed CSR build (no node-level global atomics anywhere) ----
#define NBUK 196             // ceil(50000/256), bucket = node >> 8
#define CAP  16384           // slack per bucket (mean 8192, sd ~90)
#define PB1  512
#define CHUNK1 (N_EDGES / PB1)   // 3125 exact

// W transposes (3x, k-permuted for layers 2&3) + gfill init + pooled zero, one launch.
__global__ __launch_bounds__(256) void prep_k(const float* __restrict__ W1,
                                              const float* __restrict__ W2,
                                              const float* __restrict__ W3,
                                              ushort* __restrict__ wt,
                                              int* __restrict__ gfill,
                                              float* __restrict__ pooled) {
    int blk = blockIdx.x;
    if (blk < 192) {
        int w = blk >> 6;
        const float* W = (w == 0) ? W1 : (w == 1) ? W2 : W3;
        ushort* o = wt + w * (DIM * DIM);
        int t = (blk & 63) * 256 + threadIdx.x;   // 0..16383
        int n = t >> 7, kp = t & 127;
        int f = (w == 0) ? kp : permf(kp);   // layer 1 A is true-order; 2,3 p-order
        o[n * 128 + kp] = f2b(W[f * 128 + n]);
    } else if (blk == 192) {
        int t = threadIdx.x;
        if (t < NBUK) gfill[t] = t * CAP;
    } else {
        int t = (blk - 193) * 256 + threadIdx.x;   // zero pooled + counts
        if (t < N_GRAPHS * DIM + N_GRAPHS) pooled[t] = 0.f;
    }
}

__global__ __launch_bounds__(256) void bin_k(const int* __restrict__ col,
                                             const int* __restrict__ row,
                                             int* __restrict__ gfill,
                                             uint32* __restrict__ packed) {
    __shared__ int hist[NBUK];
    __shared__ int cur[NBUK];
    int tid = threadIdx.x;
    for (int t = tid; t < NBUK; t += 256) hist[t] = 0;
    __syncthreads();
    int start = blockIdx.x * CHUNK1, end = start + CHUNK1;
    for (int e = start + tid; e < end; e += 256)
        atomicAdd(&hist[col[e] >> 8], 1);
    __syncthreads();
    for (int t = tid; t < NBUK; t += 256) {
        int h = hist[t];
        cur[t] = h ? atomicAdd(&gfill[t], h) : 0;
    }
    __syncthreads();
    for (int e = start + tid; e < end; e += 256) {
        int c = col[e];
        int r = row[e];
        int pos = atomicAdd(&cur[c >> 8], 1);
        packed[pos] = ((uint32)(c & 255) << 16) | (uint32)r;
    }
}

// per bucket: inline bucket-base scan, histogram -> cnt/offs/dis, rank-scatter csr (ushort).
__global__ __launch_bounds__(256) void bucket_k(const uint32* __restrict__ packed,
                                                const int* __restrict__ gfill,
                                                int* __restrict__ cnt,
                                                int* __restrict__ offs,
                                                float* __restrict__ dis,
                                                ushort* __restrict__ csr) {
    __shared__ int bsm[256];
    __shared__ int hist[256];
    __shared__ int sm[256];
    __shared__ int lo[256];
    __shared__ int rank[256];
    int b = blockIdx.x, tid = threadIdx.x;

    int bsz = (tid < NBUK) ? (gfill[tid] - tid * CAP) : 0;
    bsm[tid] = bsz;
    __syncthreads();
    for (int off = 1; off < 256; off <<= 1) {
        int u = 0;
        if (tid >= off) u = bsm[tid - off];
        __syncthreads();
        if (tid >= off) bsm[tid] += u;
        __syncthreads();
    }
    int size = gfill[b] - b * CAP;
    int gb = bsm[b] - size;   // exclusive base of this bucket

    const uint32* pk = packed + (size_t)b * CAP;
    hist[tid] = 0; rank[tid] = 0;
    __syncthreads();
    for (int e = tid; e < size; e += 256) atomicAdd(&hist[pk[e] >> 16], 1);
    __syncthreads();
    int h = hist[tid];
    sm[tid] = h;
    __syncthreads();
    for (int off = 1; off < 256; off <<= 1) {
        int u = 0;
        if (tid >= off) u = sm[tid - off];
        __syncthreads();
        if (tid >= off) sm[tid] += u;
        __syncthreads();
    }
    lo[tid] = sm[tid] - h;
    int node = (b << 8) + tid;
    if (node < N_NODES) {
        cnt[node]  = h;
        offs[node] = gb + lo[tid];
        dis[node]  = rsqrtf((float)h + 1.0f);
    }
    __syncthreads();
    for (int e = tid; e < size; e += 256) {
        uint32 p = pk[e];
        int cl = p >> 16;
        int r = atomicAdd(&rank[cl], 1);
        csr[gb + lo[cl] + r] = (ushort)(p & 0xffffu);
    }
}

// ---------------- fp32 -> bf16 convert ----------------
__global__ __launch_bounds__(256) void conv_k(const float* __restrict__ x, ushort* __restrict__ xb) {
    int i = blockIdx.x * blockDim.x + threadIdx.x;
    const int n4 = N_NODES * DIM / 4;
    if (i >= n4) return;
    float4 v = ((const float4*)x)[i];
    ushort4 o;
    o.x = f2b(v.x); o.y = f2b(v.y); o.z = f2b(v.z); o.w = f2b(v.w);
    ((ushort4*)xb)[i] = o;
}

// ---------------- g = fp8e5m2( (h @ W) * dis )  via MFMA ----------------
// 4 waves/block; wave = 32 rows x 128 cols. Output stored in p-order:
// feature f=nt*16+m goes to byte p=m*8+nt -> lane's 8 bytes contiguous -> uint2 store.
__global__ __launch_bounds__(256) void gemm_mfma_k(const ushort* __restrict__ xb,
                                                   const ushort* __restrict__ wt,
                                                   const float* __restrict__ dis,
                                                   unsigned char* __restrict__ gb) {
    int wid  = threadIdx.x >> 6;
    int lane = threadIdx.x & 63;
    int r0 = blockIdx.x * 128 + wid * 32;
    int m  = lane & 15;
    int kg = lane >> 4;

    int arow0 = r0 + m;
    int arow1 = r0 + 16 + m;
    if (arow0 >= N_NODES) arow0 = N_NODES - 1;   // clamp; stores guarded
    if (arow1 >= N_NODES) arow1 = N_NODES - 1;
    const ushort* abase0 = xb + (size_t)arow0 * DIM + kg * 8;
    const ushort* abase1 = xb + (size_t)arow1 * DIM + kg * 8;
    const ushort* wbase  = wt + (size_t)m * DIM + kg * 8;

    f32x4 acc[2][8];
    #pragma unroll
    for (int hh = 0; hh < 2; ++hh)
        #pragma unroll
        for (int nt = 0; nt < 8; ++nt) acc[hh][nt] = (f32x4){0.f, 0.f, 0.f, 0.f};

    #pragma unroll
    for (int kb = 0; kb < 4; ++kb) {
        bf16x8 a0 = *(const bf16x8*)(abase0 + kb * 32);
        bf16x8 a1 = *(const bf16x8*)(abase1 + kb * 32);
        #pragma unroll
        for (int nt = 0; nt < 8; ++nt) {
            bf16x8 b = *(const bf16x8*)(wbase + (size_t)nt * 16 * DIM + kb * 32);
            acc[0][nt] = __builtin_amdgcn_mfma_f32_16x16x32_bf16(a0, b, acc[0][nt], 0, 0, 0);
            acc[1][nt] = __builtin_amdgcn_mfma_f32_16x16x32_bf16(a1, b, acc[1][nt], 0, 0, 0);
        }
    }

    #pragma unroll
    for (int hh = 0; hh < 2; ++hh) {
        int orow0 = r0 + hh * 16 + kg * 4;
        #pragma unroll
        for (int i = 0; i < 4; ++i) {
            int rr = orow0 + i;
            if (rr >= N_NODES) continue;
            float dsc = dis[rr];
            uint32 u0 = (uint32)f2e5(acc[hh][0][i] * dsc)
                      | ((uint32)f2e5(acc[hh][1][i] * dsc) << 8)
                      | ((uint32)f2e5(acc[hh][2][i] * dsc) << 16)
                      | ((uint32)f2e5(acc[hh][3][i] * dsc) << 24);
            uint32 u1 = (uint32)f2e5(acc[hh][4][i] * dsc)
                      | ((uint32)f2e5(acc[hh][5][i] * dsc) << 8)
                      | ((uint32)f2e5(acc[hh][6][i] * dsc) << 16)
                      | ((uint32)f2e5(acc[hh][7][i] * dsc) << 24);
            uint2 u = make_uint2(u0, u1);
            *(uint2*)(gb + (size_t)rr * DIM + m * 8) = u;
        }
    }
}

// ---------------- out = bf16( relu(dis_i * (g_i + sum_j g_j) + b) ) ----------------
// Round-12 structure: 2 edges per VMEM, uniform broadcast shfl + cndmask,
// 8 loads (16 edges) in flight; perm decode + v_pk_add_f16.
__global__ __launch_bounds__(256) void agg_k(const unsigned char* __restrict__ gb,
                                             const float* __restrict__ dis,
                                             const ushort* __restrict__ csr,
                                             const int* __restrict__ offs,
                                             const int* __restrict__ cnt,
                                             const float* __restrict__ bias,
                                             ushort* __restrict__ outb) {
    int lane = threadIdx.x & 63;
    int node = blockIdx.x * 4 + (threadIdx.x >> 6);
    if (node >= N_NODES) return;
    int hi = lane >> 5;
    uint32 c4 = (uint32)(lane & 31) << 2;        // byte offset of this lane's 4-feature group
    const unsigned char* gq = gb + c4;

    // self term: both halves load, upper half zero-masked
    uint32 sv = *(const uint32*)(gq + ((uint32)node << 7));
    if (hi) sv = 0;
    __half2 a0 = dec01(sv), b0 = dec23(sv);
    __half2 a1 = u2h2(0),   b1 = u2h2(0);

    int base = offs[node];
    int c = cnt[node];
    for (int s0 = 0; s0 < c; s0 += 64) {
        int rem = c - s0;
        int m = rem < 64 ? rem : 64;
        int idx = 0;
        if (lane < m) idx = csr[base + s0 + lane];
        int t = 0;
        for (; t + 16 <= m; t += 16) {
            uint32 v[8];
            #pragma unroll
            for (int p = 0; p < 8; ++p) {
                int j0 = __shfl(idx, t + 2 * p, 64);
                int j1 = __shfl(idx, t + 2 * p + 1, 64);
                int jr = hi ? j1 : j0;
                v[p] = *(const uint32*)(gq + ((uint32)jr << 7));
            }
            #pragma unroll
            for (int p = 0; p < 8; ++p) {
                if (p & 1) { a1 = __hadd2(a1, dec01(v[p])); b1 = __hadd2(b1, dec23(v[p])); }
                else       { a0 = __hadd2(a0, dec01(v[p])); b0 = __hadd2(b0, dec23(v[p])); }
            }
        }
        for (; t + 2 <= m; t += 2) {
            int j0 = __shfl(idx, t, 64);
            int j1 = __shfl(idx, t + 1, 64);
            int jr = hi ? j1 : j0;
            uint32 v = *(const uint32*)(gq + ((uint32)jr << 7));
            a0 = __hadd2(a0, dec01(v)); b0 = __hadd2(b0, dec23(v));
        }
        if (t < m) {   // odd tail: upper half zero-masked
            int j = __shfl(idx, t, 64);
            uint32 v = *(const uint32*)(gq + ((uint32)j << 7));
            if (hi) v = 0;
            a0 = __hadd2(a0, dec01(v)); b0 = __hadd2(b0, dec23(v));
        }
    }

    __half2 accA = __hadd2(a0, a1);
    __half2 accB = __hadd2(b0, b1);
    accA = __hadd2(accA, u2h2((uint32)__shfl_xor((int)h2u(accA), 32, 64)));
    accB = __hadd2(accB, u2h2((uint32)__shfl_xor((int)h2u(accB), 32, 64)));

    if (hi == 0) {
        float f0 = __low2float(accA), f1 = __high2float(accA);
        float f2 = __low2float(accB), f3 = __high2float(accB);
        float d = dis[node];
        float bv0 = bias[permf(c4 + 0)];
        float bv1 = bias[permf(c4 + 1)];
        float bv2 = bias[permf(c4 + 2)];
        float bv3 = bias[permf(c4 + 3)];
        ushort4 o;
        o.x = f2b(fmaxf(fmaf(f0, d, bv0), 0.f));
        o.y = f2b(fmaxf(fmaf(f1, d, bv1), 0.f));
        o.z = f2b(fmaxf(fmaf(f2, d, bv2), 0.f));
        o.w = f2b(fmaxf(fmaf(f3, d, bv3), 0.f));
        *(ushort4*)(outb + ((size_t)node << 7) + c4) = o;
    }
}

// ---------------- mean-pool (h in p-order; pooled stays p-order) ----------------
#define POOL_BLOCKS 1024
__global__ __launch_bounds__(128) void pool_k(const ushort* __restrict__ hb,
                                              const int* __restrict__ batch,
                                              float* __restrict__ pooled,
                                              float* __restrict__ counts) {
    const int chunk = (N_NODES + POOL_BLOCKS - 1) / POOL_BLOCKS;  // 49
    int tid = threadIdx.x;
    int start = blockIdx.x * chunk;
    int end = start + chunk; if (end > N_NODES) end = N_NODES;
    if (start >= end) return;

    float acc = 0.f;
    int cur = batch[start];
    int cl = 0;
    for (int n = start; n < end; ++n) {
        int b = batch[n];
        if (b != cur) {
            atomicAdd(&pooled[cur * DIM + tid], acc);
            if (tid == 0) atomicAdd(&counts[cur], (float)cl);
            acc = 0.f; cl = 0; cur = b;
        }
        acc += b2f(hb[((size_t)n << 7) + tid]);
        ++cl;
    }
    atomicAdd(&pooled[cur * DIM + tid], acc);
    if (tid == 0) atomicAdd(&counts[cur], (float)cl);
}

// ---------------- head (pooled in p-order -> permute Wf) ----------------
__global__ void final_k(const float* __restrict__ pooled, const float* __restrict__ counts,
                        const float* __restrict__ Wf, const float* __restrict__ bf,
                        float* __restrict__ out) {
    __shared__ float sred[2];
    int gidx = blockIdx.x;
    int tid = threadIdx.x;   // 128
    float c = fmaxf(counts[gidx], 1.0f);
    float v = pooled[gidx * DIM + tid] / c * Wf[permf(tid)];
    for (int off = 32; off > 0; off >>= 1) v += __shfl_down(v, off, 64);
    if ((tid & 63) == 0) sred[tid >> 6] = v;
    __syncthreads();
    if (tid == 0) {
        float t = sred[0] + sred[1] + bf[0];
        out[gidx] = 1.0f / (1.0f + expf(-t));
    }
}

extern "C" void kernel_launch(void* const* d_in, const int* in_sizes, int n_in,
                              void* d_out, int out_size, void* d_ws, size_t ws_size,
                              hipStream_t stream) {
    const float* x     = (const float*)d_in[0];
    const int*   ei    = (const int*)d_in[1];
    const int*   batch = (const int*)d_in[2];
    const float* W1 = (const float*)d_in[3];  const float* b1 = (const float*)d_in[4];
    const float* W2 = (const float*)d_in[5];  const float* b2 = (const float*)d_in[6];
    const float* W3 = (const float*)d_in[7];  const float* b3 = (const float*)d_in[8];
    const float* Wf = (const float*)d_in[9];  const float* bf = (const float*)d_in[10];
    const int* rowp = ei;              // sources
    const int* colp = ei + N_EDGES;    // targets

    char* ws = (char*)d_ws;
    size_t o = 0;
    auto alloc = [&](size_t bytes) -> void* {
        void* p = ws + o;
        o += (bytes + 255) & ~(size_t)255;
        return p;
    };
    int*    cnt    = (int*)   alloc((size_t)N_NODES * 4);
    int*    offs   = (int*)   alloc((size_t)N_NODES * 4);
    int*    gfill  = (int*)   alloc(256 * 4);
    float*  dis    = (float*) alloc((size_t)N_NODES * 4);
    ushort* csr    = (ushort*)alloc((size_t)N_EDGES * 2);
    uint32* packed = (uint32*)alloc((size_t)NBUK * CAP * 4);
    float*  pooled = (float*) alloc((size_t)(N_GRAPHS * DIM + N_GRAPHS) * 4);
    ushort* wt     = (ushort*)alloc((size_t)3 * DIM * DIM * 2);
    unsigned char* bufA = (unsigned char*)alloc((size_t)N_NODES * DIM);  // g (fp8, p-order)
    ushort* bufB   = (ushort*)alloc((size_t)N_NODES * DIM * 2);          // h (bf16)
    float*  counts = pooled + N_GRAPHS * DIM;

    prep_k<<<226, 256, 0, stream>>>(W1, W2, W3, wt, gfill, pooled);
    bin_k<<<PB1, 256, 0, stream>>>(colp, rowp, gfill, packed);
    bucket_k<<<NBUK, 256, 0, stream>>>(packed, gfill, cnt, offs, dis, csr);

    conv_k<<<(N_NODES * DIM / 4 + 255) / 256, 256, 0, stream>>>(x, bufB);

    const int GB = (N_NODES + 127) / 128;   // 391

    // layer 1
    gemm_mfma_k<<<GB, 256, 0, stream>>>(bufB, wt, dis, bufA);
    agg_k<<<(N_NODES + 3) / 4, 256, 0, stream>>>(bufA, dis, csr, offs, cnt, b1, bufB);
    // layer 2
    gemm_mfma_k<<<GB, 256, 0, stream>>>(bufB, wt + DIM * DIM, dis, bufA);
    agg_k<<<(N_NODES + 3) / 4, 256, 0, stream>>>(bufA, dis, csr, offs, cnt, b2, bufB);
    // layer 3
    gemm_mfma_k<<<GB, 256, 0, stream>>>(bufB, wt + 2 * DIM * DIM, dis, bufA);
    agg_k<<<(N_NODES + 3) / 4, 256, 0, stream>>>(bufA, dis, csr, offs, cnt, b3, bufB);

    pool_k<<<POOL_BLOCKS, 128, 0, stream>>>(bufB, batch, pooled, counts);
    final_k<<<N_GRAPHS, 128, 0, stream>>>(pooled, counts, Wf, bf, (float*)d_out);
}

// Round 16
// 232.219 us; speedup vs baseline: 1.0584x; 1.0312x over previous
//
#include <hip/hip_runtime.h>
#include <hip/hip_fp16.h>
#include <math.h>

#define N_NODES 50000
#define N_EDGES 1600000
#define DIM     128
#define N_GRAPHS 64

typedef unsigned int uint32;
typedef __attribute__((ext_vector_type(8))) short bf16x8;
typedef __attribute__((ext_vector_type(4))) float f32x4;

static __device__ __forceinline__ ushort f2b(float f) {
    uint32 u = __float_as_uint(f);
    uint32 r = (u + 0x7fffu + ((u >> 16) & 1u)) >> 16;   // RNE
    return (ushort)r;
}
static __device__ __forceinline__ float b2f(ushort h) {
    return __uint_as_float(((uint32)h) << 16);
}
// fp8 e5m2 = top byte of fp16. Encode f32 -> f16 (RNE) -> RNE to top byte.
static __device__ __forceinline__ unsigned char f2e5(float f) {
    ushort hb = __half_as_ushort(__float2half(f));
    return (unsigned char)(((uint32)hb + 0x7fu + ((hb >> 8) & 1u)) >> 8);
}
// packed pair: f32x2 -> fp16x2 (RTZ) -> +RNE offset toward e5m2 in the high byte of each half
static __device__ __forceinline__ uint32 pk2(float a, float b) {
    auto h = __builtin_amdgcn_cvt_pkrtz(a, b);   // __fp16 ext_vector(2)
    uint32 u;
    __builtin_memcpy(&u, &h, 4);
    return u + 0x007F007Fu + ((u >> 8) & 0x00010001u);
}
union h2u_t { uint32 u; __half2 h; };
static __device__ __forceinline__ __half2 u2h2(uint32 u) { h2u_t t; t.u = u; return t.h; }
static __device__ __forceinline__ uint32 h2u(__half2 h)  { h2u_t t; t.h = h; return t.u; }
// bytes {0,1} / {2,3} of v -> fp16 pair (each byte into high byte of an fp16)
static __device__ __forceinline__ __half2 dec01(uint32 v) {
    return u2h2(__builtin_amdgcn_perm(v, 0u, 0x05000400u));
}
static __device__ __forceinline__ __half2 dec23(uint32 v) {
    return u2h2(__builtin_amdgcn_perm(v, 0u, 0x07000600u));
}
// stored position p -> true feature index (p = m*8 + nt, f = nt*16 + m)
static __device__ __forceinline__ int permf(int p) { return ((p & 7) << 4) + (p >> 3); }

// ---- bucketed CSR build (no node-level global atomics anywhere) ----
#define NBUK 196             // ceil(50000/256), bucket = node >> 8
#define CAP  16384           // slack per bucket (mean 8192, sd ~90)
#define PB1  512
#define CHUNK1 (N_EDGES / PB1)   // 3125 exact

// conv (x->bf16) + W transposes (3x, k-permuted for layers 2&3) + gfill + pooled zero.
#define PREP_CONV 6250           // 1.6M float4 groups / 256 exact
__global__ __launch_bounds__(256) void prep_k(const float* __restrict__ x,
                                              ushort* __restrict__ xb,
                                              const float* __restrict__ W1,
                                              const float* __restrict__ W2,
                                              const float* __restrict__ W3,
                                              ushort* __restrict__ wt,
                                              int* __restrict__ gfill,
                                              float* __restrict__ pooled) {
    int blk = blockIdx.x;
    if (blk < PREP_CONV) {
        int i = blk * 256 + threadIdx.x;
        float4 v = ((const float4*)x)[i];
        ushort4 o;
        o.x = f2b(v.x); o.y = f2b(v.y); o.z = f2b(v.z); o.w = f2b(v.w);
        ((ushort4*)xb)[i] = o;
    } else if (blk < PREP_CONV + 192) {
        int b2 = blk - PREP_CONV;
        int w = b2 >> 6;
        const float* W = (w == 0) ? W1 : (w == 1) ? W2 : W3;
        ushort* o = wt + w * (DIM * DIM);
        int t = (b2 & 63) * 256 + threadIdx.x;   // 0..16383
        int n = t >> 7, kp = t & 127;
        int f = (w == 0) ? kp : permf(kp);   // layer 1 A is true-order; 2,3 p-order
        o[n * 128 + kp] = f2b(W[f * 128 + n]);
    } else if (blk == PREP_CONV + 192) {
        int t = threadIdx.x;
        if (t < NBUK) gfill[t] = t * CAP;
    } else {
        int t = (blk - (PREP_CONV + 193)) * 256 + threadIdx.x;   // zero pooled + counts
        if (t < N_GRAPHS * DIM + N_GRAPHS) pooled[t] = 0.f;
    }
}
#define PREP_BLOCKS (PREP_CONV + 193 + 33)

// pass 1: single global read; stage packed edges in LDS; histogram + reserve + scatter.
__global__ __launch_bounds__(256) void bin_k(const int* __restrict__ col,
                                             const int* __restrict__ row,
                                             int* __restrict__ gfill,
                                             uint32* __restrict__ packed) {
    __shared__ uint32 epk[CHUNK1];   // 12.5 KB
    __shared__ int hist[NBUK];
    __shared__ int cur[NBUK];
    int tid = threadIdx.x;
    for (int t = tid; t < NBUK; t += 256) hist[t] = 0;
    __syncthreads();
    int start = blockIdx.x * CHUNK1;
    for (int k = tid; k < CHUNK1; k += 256) {
        int c = col[start + k];
        int r = row[start + k];
        epk[k] = ((uint32)c << 16) | (uint32)r;   // c,r < 65536
        atomicAdd(&hist[c >> 8], 1);
    }
    __syncthreads();
    for (int t = tid; t < NBUK; t += 256) {
        int h = hist[t];
        cur[t] = h ? atomicAdd(&gfill[t], h) : 0;
    }
    __syncthreads();
    for (int k = tid; k < CHUNK1; k += 256) {
        uint32 p = epk[k];
        int bu = p >> 24;                      // c >> 8
        int pos = atomicAdd(&cur[bu], 1);
        packed[pos] = p & 0x00FFFFFFu;         // (c&255)<<16 | r
    }
}

// per bucket: inline bucket-base scan, histogram -> cnt/offs/dis, rank-scatter csr (ushort).
__global__ __launch_bounds__(256) void bucket_k(const uint32* __restrict__ packed,
                                                const int* __restrict__ gfill,
                                                int* __restrict__ cnt,
                                                int* __restrict__ offs,
                                                float* __restrict__ dis,
                                                ushort* __restrict__ csr) {
    __shared__ int bsm[256];
    __shared__ int hist[256];
    __shared__ int sm[256];
    __shared__ int lo[256];
    __shared__ int rank[256];
    int b = blockIdx.x, tid = threadIdx.x;

    int bsz = (tid < NBUK) ? (gfill[tid] - tid * CAP) : 0;
    bsm[tid] = bsz;
    __syncthreads();
    for (int off = 1; off < 256; off <<= 1) {
        int u = 0;
        if (tid >= off) u = bsm[tid - off];
        __syncthreads();
        if (tid >= off) bsm[tid] += u;
        __syncthreads();
    }
    int size = gfill[b] - b * CAP;
    int gb = bsm[b] - size;   // exclusive base of this bucket

    const uint32* pk = packed + (size_t)b * CAP;
    hist[tid] = 0; rank[tid] = 0;
    __syncthreads();
    for (int e = tid; e < size; e += 256) atomicAdd(&hist[pk[e] >> 16], 1);
    __syncthreads();
    int h = hist[tid];
    sm[tid] = h;
    __syncthreads();
    for (int off = 1; off < 256; off <<= 1) {
        int u = 0;
        if (tid >= off) u = sm[tid - off];
        __syncthreads();
        if (tid >= off) sm[tid] += u;
        __syncthreads();
    }
    lo[tid] = sm[tid] - h;
    int node = (b << 8) + tid;
    if (node < N_NODES) {
        cnt[node]  = h;
        offs[node] = gb + lo[tid];
        dis[node]  = rsqrtf((float)h + 1.0f);
    }
    __syncthreads();
    for (int e = tid; e < size; e += 256) {
        uint32 p = pk[e];
        int cl = p >> 16;
        int r = atomicAdd(&rank[cl], 1);
        csr[gb + lo[cl] + r] = (ushort)(p & 0xffffu);
    }
}

// ---------------- g = fp8e5m2( (h @ W) * dis )  via MFMA ----------------
// 4 waves/block; wave = 32 rows x 128 cols. Output stored in p-order:
// feature f=nt*16+m goes to byte p=m*8+nt -> lane's 8 bytes contiguous -> uint2 store.
// Epilogue packs via v_cvt_pkrtz + packed RNE + v_perm (byte1/byte3 of each pair).
__global__ __launch_bounds__(256) void gemm_mfma_k(const ushort* __restrict__ xb,
                                                   const ushort* __restrict__ wt,
                                                   const float* __restrict__ dis,
                                                   unsigned char* __restrict__ gb) {
    int wid  = threadIdx.x >> 6;
    int lane = threadIdx.x & 63;
    int r0 = blockIdx.x * 128 + wid * 32;
    int m  = lane & 15;
    int kg = lane >> 4;

    int arow0 = r0 + m;
    int arow1 = r0 + 16 + m;
    if (arow0 >= N_NODES) arow0 = N_NODES - 1;   // clamp; stores guarded
    if (arow1 >= N_NODES) arow1 = N_NODES - 1;
    const ushort* abase0 = xb + (size_t)arow0 * DIM + kg * 8;
    const ushort* abase1 = xb + (size_t)arow1 * DIM + kg * 8;
    const ushort* wbase  = wt + (size_t)m * DIM + kg * 8;

    f32x4 acc[2][8];
    #pragma unroll
    for (int hh = 0; hh < 2; ++hh)
        #pragma unroll
        for (int nt = 0; nt < 8; ++nt) acc[hh][nt] = (f32x4){0.f, 0.f, 0.f, 0.f};

    #pragma unroll
    for (int kb = 0; kb < 4; ++kb) {
        bf16x8 a0 = *(const bf16x8*)(abase0 + kb * 32);
        bf16x8 a1 = *(const bf16x8*)(abase1 + kb * 32);
        #pragma unroll
        for (int nt = 0; nt < 8; ++nt) {
            bf16x8 b = *(const bf16x8*)(wbase + (size_t)nt * 16 * DIM + kb * 32);
            acc[0][nt] = __builtin_amdgcn_mfma_f32_16x16x32_bf16(a0, b, acc[0][nt], 0, 0, 0);
            acc[1][nt] = __builtin_amdgcn_mfma_f32_16x16x32_bf16(a1, b, acc[1][nt], 0, 0, 0);
        }
    }

    #pragma unroll
    for (int hh = 0; hh < 2; ++hh) {
        int orow0 = r0 + hh * 16 + kg * 4;
        #pragma unroll
        for (int i = 0; i < 4; ++i) {
            int rr = orow0 + i;
            if (rr >= N_NODES) continue;
            float dsc = dis[rr];
            uint32 uA = pk2(acc[hh][0][i] * dsc, acc[hh][1][i] * dsc);
            uint32 uB = pk2(acc[hh][2][i] * dsc, acc[hh][3][i] * dsc);
            uint32 uC = pk2(acc[hh][4][i] * dsc, acc[hh][5][i] * dsc);
            uint32 uD = pk2(acc[hh][6][i] * dsc, acc[hh][7][i] * dsc);
            uint2 u;
            u.x = __builtin_amdgcn_perm(uB, uA, 0x07050301u);
            u.y = __builtin_amdgcn_perm(uD, uC, 0x07050301u);
            *(uint2*)(gb + (size_t)rr * DIM + m * 8) = u;
        }
    }
}

// ---------------- out = bf16( relu(dis_i * (g_i + sum_j g_j) + b) ) ----------------
// Round-12 structure: 2 edges per VMEM, uniform broadcast shfl + cndmask,
// 8 loads (16 edges) in flight; perm decode + v_pk_add_f16.
__global__ __launch_bounds__(256) void agg_k(const unsigned char* __restrict__ gb,
                                             const float* __restrict__ dis,
                                             const ushort* __restrict__ csr,
                                             const int* __restrict__ offs,
                                             const int* __restrict__ cnt,
                                             const float* __restrict__ bias,
                                             ushort* __restrict__ outb) {
    int lane = threadIdx.x & 63;
    int node = blockIdx.x * 4 + (threadIdx.x >> 6);
    if (node >= N_NODES) return;
    int hi = lane >> 5;
    uint32 c4 = (uint32)(lane & 31) << 2;        // byte offset of this lane's 4-feature group
    const unsigned char* gq = gb + c4;

    // self term: both halves load, upper half zero-masked
    uint32 sv = *(const uint32*)(gq + ((uint32)node << 7));
    if (hi) sv = 0;
    __half2 a0 = dec01(sv), b0 = dec23(sv);
    __half2 a1 = u2h2(0),   b1 = u2h2(0);

    int base = offs[node];
    int c = cnt[node];
    for (int s0 = 0; s0 < c; s0 += 64) {
        int rem = c - s0;
        int m = rem < 64 ? rem : 64;
        int idx = 0;
        if (lane < m) idx = csr[base + s0 + lane];
        int t = 0;
        for (; t + 16 <= m; t += 16) {
            uint32 v[8];
            #pragma unroll
            for (int p = 0; p < 8; ++p) {
                int j0 = __shfl(idx, t + 2 * p, 64);
                int j1 = __shfl(idx, t + 2 * p + 1, 64);
                int jr = hi ? j1 : j0;
                v[p] = *(const uint32*)(gq + ((uint32)jr << 7));
            }
            #pragma unroll
            for (int p = 0; p < 8; ++p) {
                if (p & 1) { a1 = __hadd2(a1, dec01(v[p])); b1 = __hadd2(b1, dec23(v[p])); }
                else       { a0 = __hadd2(a0, dec01(v[p])); b0 = __hadd2(b0, dec23(v[p])); }
            }
        }
        for (; t + 2 <= m; t += 2) {
            int j0 = __shfl(idx, t, 64);
            int j1 = __shfl(idx, t + 1, 64);
            int jr = hi ? j1 : j0;
            uint32 v = *(const uint32*)(gq + ((uint32)jr << 7));
            a0 = __hadd2(a0, dec01(v)); b0 = __hadd2(b0, dec23(v));
        }
        if (t < m) {   // odd tail: upper half zero-masked
            int j = __shfl(idx, t, 64);
            uint32 v = *(const uint32*)(gq + ((uint32)j << 7));
            if (hi) v = 0;
            a0 = __hadd2(a0, dec01(v)); b0 = __hadd2(b0, dec23(v));
        }
    }

    __half2 accA = __hadd2(a0, a1);
    __half2 accB = __hadd2(b0, b1);
    accA = __hadd2(accA, u2h2((uint32)__shfl_xor((int)h2u(accA), 32, 64)));
    accB = __hadd2(accB, u2h2((uint32)__shfl_xor((int)h2u(accB), 32, 64)));

    if (hi == 0) {
        float f0 = __low2float(accA), f1 = __high2float(accA);
        float f2 = __low2float(accB), f3 = __high2float(accB);
        float d = dis[node];
        float bv0 = bias[permf(c4 + 0)];
        float bv1 = bias[permf(c4 + 1)];
        float bv2 = bias[permf(c4 + 2)];
        float bv3 = bias[permf(c4 + 3)];
        ushort4 o;
        o.x = f2b(fmaxf(fmaf(f0, d, bv0), 0.f));
        o.y = f2b(fmaxf(fmaf(f1, d, bv1), 0.f));
        o.z = f2b(fmaxf(fmaf(f2, d, bv2), 0.f));
        o.w = f2b(fmaxf(fmaf(f3, d, bv3), 0.f));
        *(ushort4*)(outb + ((size_t)node << 7) + c4) = o;
    }
}

// ---------------- mean-pool (h in p-order; pooled stays p-order) ----------------
#define POOL_BLOCKS 1024
__global__ __launch_bounds__(128) void pool_k(const ushort* __restrict__ hb,
                                              const int* __restrict__ batch,
                                              float* __restrict__ pooled,
                                              float* __restrict__ counts) {
    const int chunk = (N_NODES + POOL_BLOCKS - 1) / POOL_BLOCKS;  // 49
    int tid = threadIdx.x;
    int start = blockIdx.x * chunk;
    int end = start + chunk; if (end > N_NODES) end = N_NODES;
    if (start >= end) return;

    float acc = 0.f;
    int cur = batch[start];
    int cl = 0;
    for (int n = start; n < end; ++n) {
        int b = batch[n];
        if (b != cur) {
            atomicAdd(&pooled[cur * DIM + tid], acc);
            if (tid == 0) atomicAdd(&counts[cur], (float)cl);
            acc = 0.f; cl = 0; cur = b;
        }
        acc += b2f(hb[((size_t)n << 7) + tid]);
        ++cl;
    }
    atomicAdd(&pooled[cur * DIM + tid], acc);
    if (tid == 0) atomicAdd(&counts[cur], (float)cl);
}

// ---------------- head (pooled in p-order -> permute Wf) ----------------
__global__ void final_k(const float* __restrict__ pooled, const float* __restrict__ counts,
                        const float* __restrict__ Wf, const float* __restrict__ bf,
                        float* __restrict__ out) {
    __shared__ float sred[2];
    int gidx = blockIdx.x;
    int tid = threadIdx.x;   // 128
    float c = fmaxf(counts[gidx], 1.0f);
    float v = pooled[gidx * DIM + tid] / c * Wf[permf(tid)];
    for (int off = 32; off > 0; off >>= 1) v += __shfl_down(v, off, 64);
    if ((tid & 63) == 0) sred[tid >> 6] = v;
    __syncthreads();
    if (tid == 0) {
        float t = sred[0] + sred[1] + bf[0];
        out[gidx] = 1.0f / (1.0f + expf(-t));
    }
}

extern "C" void kernel_launch(void* const* d_in, const int* in_sizes, int n_in,
                              void* d_out, int out_size, void* d_ws, size_t ws_size,
                              hipStream_t stream) {
    const float* x     = (const float*)d_in[0];
    const int*   ei    = (const int*)d_in[1];
    const int*   batch = (const int*)d_in[2];
    const float* W1 = (const float*)d_in[3];  const float* b1 = (const float*)d_in[4];
    const float* W2 = (const float*)d_in[5];  const float* b2 = (const float*)d_in[6];
    const float* W3 = (const float*)d_in[7];  const float* b3 = (const float*)d_in[8];
    const float* Wf = (const float*)d_in[9];  const float* bf = (const float*)d_in[10];
    const int* rowp = ei;              // sources
    const int* colp = ei + N_EDGES;    // targets

    char* ws = (char*)d_ws;
    size_t o = 0;
    auto alloc = [&](size_t bytes) -> void* {
        void* p = ws + o;
        o += (bytes + 255) & ~(size_t)255;
        return p;
    };
    int*    cnt    = (int*)   alloc((size_t)N_NODES * 4);
    int*    offs   = (int*)   alloc((size_t)N_NODES * 4);
    int*    gfill  = (int*)   alloc(256 * 4);
    float*  dis    = (float*) alloc((size_t)N_NODES * 4);
    ushort* csr    = (ushort*)alloc((size_t)N_EDGES * 2);
    uint32* packed = (uint32*)alloc((size_t)NBUK * CAP * 4);
    float*  pooled = (float*) alloc((size_t)(N_GRAPHS * DIM + N_GRAPHS) * 4);
    ushort* wt     = (ushort*)alloc((size_t)3 * DIM * DIM * 2);
    unsigned char* bufA = (unsigned char*)alloc((size_t)N_NODES * DIM);  // g (fp8, p-order)
    ushort* bufB   = (ushort*)alloc((size_t)N_NODES * DIM * 2);          // h (bf16)
    float*  counts = pooled + N_GRAPHS * DIM;

    prep_k<<<PREP_BLOCKS, 256, 0, stream>>>(x, bufB, W1, W2, W3, wt, gfill, pooled);
    bin_k<<<PB1, 256, 0, stream>>>(colp, rowp, gfill, packed);
    bucket_k<<<NBUK, 256, 0, stream>>>(packed, gfill, cnt, offs, dis, csr);

    const int GB = (N_NODES + 127) / 128;   // 391

    // layer 1
    gemm_mfma_k<<<GB, 256, 0, stream>>>(bufB, wt, dis, bufA);
    agg_k<<<(N_NODES + 3) / 4, 256, 0, stream>>>(bufA, dis, csr, offs, cnt, b1, bufB);
    // layer 2
    gemm_mfma_k<<<GB, 256, 0, stream>>>(bufB, wt + DIM * DIM, dis, bufA);
    agg_k<<<(N_NODES + 3) / 4, 256, 0, stream>>>(bufA, dis, csr, offs, cnt, b2, bufB);
    // layer 3
    gemm_mfma_k<<<GB, 256, 0, stream>>>(bufB, wt + 2 * DIM * DIM, dis, bufA);
    agg_k<<<(N_NODES + 3) / 4, 256, 0, stream>>>(bufA, dis, csr, offs, cnt, b3, bufB);

    pool_k<<<POOL_BLOCKS, 128, 0, stream>>>(bufB, batch, pooled, counts);
    final_k<<<N_GRAPHS, 128, 0, stream>>>(pooled, counts, Wf, bf, (float*)d_out);
}